// Round 1
// baseline (578.258 us; speedup 1.0000x reference)
//
#include <hip/hip_runtime.h>

#define HSZ 32
#define TSEQ 2048
#define NBATCH 256

__device__ __forceinline__ float hw_exp2(float x) {
#if __has_builtin(__builtin_amdgcn_exp2f)
    return __builtin_amdgcn_exp2f(x);
#else
    return exp2f(x);
#endif
}

__device__ __forceinline__ float hw_rcp(float x) {
#if __has_builtin(__builtin_amdgcn_rcpf)
    return __builtin_amdgcn_rcpf(x);
#else
    return 1.0f / x;
#endif
}

// sigmoid(x) = 1 / (1 + exp(-x)) = rcp(1 + exp2(-x*log2e))
__device__ __forceinline__ float fast_sigmoid(float x) {
    float e = hw_exp2(x * -1.44269504088896340736f);
    return hw_rcp(1.0f + e);
}

__global__ __launch_bounds__(64, 1) void lstm_last_kernel(
    const float* __restrict__ x,      // [B, T, 1]
    const float* __restrict__ W_ih,   // [4H, 1]
    const float* __restrict__ W_hh,   // [4H, H]
    const float* __restrict__ b_ih,   // [4H]
    const float* __restrict__ b_hh,   // [4H]
    float* __restrict__ out)          // [B, H]
{
    const int b    = blockIdx.x;
    const int l    = threadIdx.x;   // 0..63
    const int k    = l & 31;        // hidden unit index
    const int half = l >> 5;        // 0: lanes compute (i,g); 1: lanes compute (f,o)
    const int row0 = l;             // W_hh row for dot0: i_k (half0) or f_k (half1)
    const int row1 = l + 64;        // W_hh row for dot1: g_k (half0) or o_k (half1)

    __shared__ float x_lds[TSEQ];   // 8 KB: whole x row for this batch element
    __shared__ float h_lds[HSZ];    // h broadcast buffer

    // ---- one-time staging: x row into LDS (float4, coalesced) ----
    const float4* xrow4 = (const float4*)(x + (size_t)b * TSEQ);
    float4* xl4 = (float4*)x_lds;
    #pragma unroll
    for (int j = 0; j < (TSEQ / 4) / 64; ++j)   // 8 iters
        xl4[j * 64 + l] = xrow4[j * 64 + l];

    // ---- one-time: load my two W_hh rows into registers ----
    float w0[HSZ], w1[HSZ];
    #pragma unroll
    for (int j = 0; j < HSZ; j += 4) {
        float4 a = *(const float4*)(W_hh + row0 * HSZ + j);
        w0[j] = a.x; w0[j+1] = a.y; w0[j+2] = a.z; w0[j+3] = a.w;
        float4 c4 = *(const float4*)(W_hh + row1 * HSZ + j);
        w1[j] = c4.x; w1[j+1] = c4.y; w1[j+2] = c4.z; w1[j+3] = c4.w;
    }
    const float wx0   = W_ih[row0];
    const float wx1   = W_ih[row1];
    const float bias0 = b_ih[row0] + b_hh[row0];
    const float bias1 = b_ih[row1] + b_hh[row1];

    // dot1 activation: half0 wants tanh(d1) = 2*sigmoid(2*d1) - 1, half1 wants sigmoid(d1)
    const float s1scale = half ? 1.0f : 2.0f;
    const float s1mul   = half ? 1.0f : 2.0f;
    const float s1add   = half ? 0.0f : -1.0f;

    // replicated h state in registers (all compile-time indices -> VGPRs)
    float h[HSZ];
    #pragma unroll
    for (int j = 0; j < HSZ; ++j) h[j] = 0.0f;
    float c = 0.0f;
    float hk_out = 0.0f;

    __syncthreads();   // x_lds ready

    #pragma unroll 1
    for (int t = 0; t < TSEQ; ++t) {
        float xt = x_lds[t];   // wave-uniform broadcast read

        // two length-32 dots, 4 partial accumulators each (ILP)
        float p00 = fmaf(wx0, xt, bias0), p01 = 0.f, p02 = 0.f, p03 = 0.f;
        float p10 = fmaf(wx1, xt, bias1), p11 = 0.f, p12 = 0.f, p13 = 0.f;
        #pragma unroll
        for (int j = 0; j < HSZ; j += 4) {
            p00 = fmaf(w0[j],   h[j],   p00);
            p01 = fmaf(w0[j+1], h[j+1], p01);
            p02 = fmaf(w0[j+2], h[j+2], p02);
            p03 = fmaf(w0[j+3], h[j+3], p03);
            p10 = fmaf(w1[j],   h[j],   p10);
            p11 = fmaf(w1[j+1], h[j+1], p11);
            p12 = fmaf(w1[j+2], h[j+2], p12);
            p13 = fmaf(w1[j+3], h[j+3], p13);
        }
        float d0 = (p00 + p01) + (p02 + p03);   // i (half0) or f (half1), pre-activation
        float d1 = (p10 + p11) + (p12 + p13);   // g (half0) or o (half1), pre-activation

        float a0 = fast_sigmoid(d0);                     // sigmoid for both i and f
        float s1 = fast_sigmoid(s1scale * d1);
        float a1 = fmaf(s1mul, s1, s1add);               // tanh (half0) / sigmoid (half1)

        // exchange across the 32-lane halves: lane k <-> lane k+32
        float sw0 = __shfl_xor(a0, 32, 64);
        float sw1 = __shfl_xor(a1, 32, 64);

        float fg = half ? a0  : sw0;
        float ig = half ? sw0 : a0;
        float og = half ? a1  : sw1;
        float gg = half ? sw1 : a1;

        c = fmaf(fg, c, ig * gg);
        float th = fmaf(2.0f, fast_sigmoid(2.0f * c), -1.0f);  // tanh(c)
        float hk = og * th;
        hk_out = hk;

        if (half == 0) h_lds[k] = hk;
        __syncthreads();   // single wave: ~free; orders ds_write before reads

        // broadcast-reload full h into registers (8x ds_read_b128, same addr all lanes)
        #pragma unroll
        for (int j = 0; j < 8; ++j) {
            float4 v = ((const float4*)h_lds)[j];
            h[4*j+0] = v.x; h[4*j+1] = v.y; h[4*j+2] = v.z; h[4*j+3] = v.w;
        }
        // no second barrier: single-wave lockstep + per-wave in-order DS pipe;
        // next iteration's ds_write depends (via registers) on these reads.
    }

    if (half == 0) out[b * HSZ + k] = hk_out;
}

extern "C" void kernel_launch(void* const* d_in, const int* in_sizes, int n_in,
                              void* d_out, int out_size, void* d_ws, size_t ws_size,
                              hipStream_t stream) {
    const float* x    = (const float*)d_in[0];
    const float* W_ih = (const float*)d_in[1];
    const float* W_hh = (const float*)d_in[2];
    const float* b_ih = (const float*)d_in[3];
    const float* b_hh = (const float*)d_in[4];
    float* out = (float*)d_out;

    lstm_last_kernel<<<NBATCH, 64, 0, stream>>>(x, W_ih, W_hh, b_ih, b_hh, out);
}

// Round 3
// 451.077 us; speedup vs baseline: 1.2819x; 1.2819x over previous
//
#include <hip/hip_runtime.h>

#define HSZ 32
#define TSEQ 2048
#define NBATCH 256

typedef unsigned int v2u __attribute__((ext_vector_type(2)));

__device__ __forceinline__ float hw_exp2(float x) {
#if __has_builtin(__builtin_amdgcn_exp2f)
    return __builtin_amdgcn_exp2f(x);
#else
    return exp2f(x);
#endif
}

__device__ __forceinline__ float hw_rcp(float x) {
#if __has_builtin(__builtin_amdgcn_rcpf)
    return __builtin_amdgcn_rcpf(x);
#else
    return 1.0f / x;
#endif
}

// sigmoid(x) = 1 / (1 + exp(-x)) = rcp(1 + exp2(-x*log2e))
__device__ __forceinline__ float fast_sigmoid(float x) {
    return hw_rcp(1.0f + hw_exp2(x * -1.44269504088896340736f));
}

__device__ __forceinline__ float readlane_f(float v, int lane) {
    return __uint_as_float(__builtin_amdgcn_readlane(__float_as_uint(v), lane));
}

// Direction-agnostic cross-half combine: returns v[lane&31] + v[(lane&31)+32]
// in ALL lanes, regardless of which way the swap instruction moves halves.
__device__ __forceinline__ float half_sum(float v) {
#if __has_builtin(__builtin_amdgcn_permlane32_swap)
    v2u r = __builtin_amdgcn_permlane32_swap(__float_as_uint(v), __float_as_uint(v), false, false);
    return __uint_as_float(r.x) + __uint_as_float(r.y);
#else
    return v + __shfl_xor(v, 32, 64);
#endif
}

__global__ __launch_bounds__(64, 1) void lstm_last_kernel(
    const float* __restrict__ x,      // [B, T, 1]
    const float* __restrict__ W_ih,   // [4H, 1]
    const float* __restrict__ W_hh,   // [4H, H]
    const float* __restrict__ b_ih,   // [4H]
    const float* __restrict__ b_hh,   // [4H]
    float* __restrict__ out)          // [B, H]
{
    const int b    = blockIdx.x;
    const int l    = threadIdx.x;   // 0..63
    const int k    = l & 31;        // hidden unit index
    const int half = l >> 5;        // 0: rows (i_k, g_k); 1: rows (f_k, o_k)
    const int row0 = l;             // i_k (half0: rows 0..31) or f_k (half1: rows 32..63)
    const int row1 = l + 64;        // g_k (half0: rows 64..95) or o_k (half1: rows 96..127)

    __shared__ float x_lds[TSEQ + 4];   // whole x row + pad for t+1 prefetch

    // ---- one-time staging: x row into LDS (float4, coalesced) ----
    const float4* xrow4 = (const float4*)(x + (size_t)b * TSEQ);
    float4* xl4 = (float4*)x_lds;
    #pragma unroll
    for (int j = 0; j < (TSEQ / 4) / 64; ++j)   // 8 iters
        xl4[j * 64 + l] = xrow4[j * 64 + l];
    if (l == 0) x_lds[TSEQ] = 0.0f;

    // ---- one-time: my two W_hh rows into registers ----
    float w0[HSZ], w1[HSZ];
    #pragma unroll
    for (int j = 0; j < HSZ; j += 4) {
        float4 a  = *(const float4*)(W_hh + row0 * HSZ + j);
        float4 c4 = *(const float4*)(W_hh + row1 * HSZ + j);
        w0[j] = a.x;  w0[j+1] = a.y;  w0[j+2] = a.z;  w0[j+3] = a.w;
        w1[j] = c4.x; w1[j+1] = c4.y; w1[j+2] = c4.z; w1[j+3] = c4.w;
    }
    const float wx0   = W_ih[row0];
    const float wx1   = W_ih[row1];
    const float bias0 = b_ih[row0] + b_hh[row0];
    const float bias1 = b_ih[row1] + b_hh[row1];

    // dot0 -> sigmoid always (i or f).
    // dot1 -> tanh for half0 (g), sigmoid for half1 (o): tanh(x)=2*sigmoid(2x)-1
    const float s1scale = half ? 1.0f : 2.0f;
    const float s1mul   = half ? 1.0f : 2.0f;
    const float s1add   = half ? 0.0f : -1.0f;

    float c  = 0.0f;   // cell state (used by half1 lanes; updated in all)
    float hk = 0.0f;   // h_k valid in lanes 32..63 (junk in 0..31)

    __syncthreads();   // x_lds ready
    float xt = x_lds[0];

    #pragma unroll 1
    for (int t = 0; t < TSEQ; ++t) {
        // ---- broadcast h (from lanes 32..63) into uniform SGPR values ----
        float hs[HSZ];
        #pragma unroll
        for (int j = 0; j < HSZ; ++j) hs[j] = readlane_f(hk, 32 + j);

        float xt_next = x_lds[t + 1];   // prefetch (latency hidden under dots)

        // ---- two length-32 dots: VGPR weight x SGPR h (1 scalar operand ok) ----
        float p00 = fmaf(wx0, xt, bias0), p01 = 0.f, p02 = 0.f, p03 = 0.f;
        float p10 = fmaf(wx1, xt, bias1), p11 = 0.f, p12 = 0.f, p13 = 0.f;
        #pragma unroll
        for (int j = 0; j < HSZ; j += 4) {
            p00 = fmaf(w0[j],   hs[j],   p00);
            p01 = fmaf(w0[j+1], hs[j+1], p01);
            p02 = fmaf(w0[j+2], hs[j+2], p02);
            p03 = fmaf(w0[j+3], hs[j+3], p03);
            p10 = fmaf(w1[j],   hs[j],   p10);
            p11 = fmaf(w1[j+1], hs[j+1], p11);
            p12 = fmaf(w1[j+2], hs[j+2], p12);
            p13 = fmaf(w1[j+3], hs[j+3], p13);
        }
        float d0 = (p00 + p01) + (p02 + p03);   // i (half0) / f (half1)
        float d1 = (p10 + p11) + (p12 + p13);   // g (half0) / o (half1)

        float a0 = fast_sigmoid(d0);
        float a1 = fmaf(s1mul, fast_sigmoid(s1scale * d1), s1add);

        // half0 contributes i*g, half1 contributes f*c; their cross-half SUM
        // is c_new in every lane — commutative, so swap direction is irrelevant.
        float v  = half ? (a0 * c) : (a0 * a1);
        float cn = half_sum(v);
        c = cn;

        float th = fmaf(2.0f, fast_sigmoid(2.0f * cn), -1.0f);  // tanh(c_new)
        hk = a1 * th;   // half1: o * tanh(c)  (half0 lanes: junk, never read)

        xt = xt_next;
    }

    if (half) out[b * HSZ + k] = hk;
}

extern "C" void kernel_launch(void* const* d_in, const int* in_sizes, int n_in,
                              void* d_out, int out_size, void* d_ws, size_t ws_size,
                              hipStream_t stream) {
    const float* x    = (const float*)d_in[0];
    const float* W_ih = (const float*)d_in[1];
    const float* W_hh = (const float*)d_in[2];
    const float* b_ih = (const float*)d_in[3];
    const float* b_hh = (const float*)d_in[4];
    float* out = (float*)d_out;

    lstm_last_kernel<<<NBATCH, 64, 0, stream>>>(x, W_ih, W_hh, b_ih, b_hh, out);
}

// Round 4
// 423.899 us; speedup vs baseline: 1.3641x; 1.0641x over previous
//
#include <hip/hip_runtime.h>

#define HSZ 32
#define TSEQ 2048
#define NBATCH 256

typedef float v2f __attribute__((ext_vector_type(2)));
typedef unsigned int v2u __attribute__((ext_vector_type(2)));

__device__ __forceinline__ v2f make2(float a, float b) {
    v2f r; r.x = a; r.y = b; return r;
}

__device__ __forceinline__ float hw_exp2(float x) {
#if __has_builtin(__builtin_amdgcn_exp2f)
    return __builtin_amdgcn_exp2f(x);
#else
    return exp2f(x);
#endif
}

__device__ __forceinline__ float hw_rcp(float x) {
#if __has_builtin(__builtin_amdgcn_rcpf)
    return __builtin_amdgcn_rcpf(x);
#else
    return 1.0f / x;
#endif
}

__device__ __forceinline__ float readlane_f(float v, int lane) {
    return __uint_as_float(__builtin_amdgcn_readlane(__float_as_uint(v), lane));
}

// Direction-agnostic cross-half combine: returns v[lane&31] + v[(lane&31)+32]
// in ALL lanes, regardless of which way the swap moves halves. (Proven in R2.)
__device__ __forceinline__ float half_sum(float v) {
#if __has_builtin(__builtin_amdgcn_permlane32_swap)
    v2u r = __builtin_amdgcn_permlane32_swap(__float_as_uint(v), __float_as_uint(v), false, false);
    return __uint_as_float(r.x) + __uint_as_float(r.y);
#else
    return v + __shfl_xor(v, 32, 64);
#endif
}

#if __has_builtin(__builtin_elementwise_fma)
#define PKFMA(a, b, cc) __builtin_elementwise_fma((a), (b), (cc))
#else
__device__ __forceinline__ v2f PKFMA(v2f a, v2f b, v2f c) {
    return make2(fmaf(a.x, b.x, c.x), fmaf(a.y, b.y, c.y));
}
#endif

#define NL2E -1.44269504088896340736f   // -log2(e)

__global__ __launch_bounds__(64, 1) void lstm_last_kernel(
    const float* __restrict__ x,      // [B, T, 1]
    const float* __restrict__ W_ih,   // [4H, 1]
    const float* __restrict__ W_hh,   // [4H, H]
    const float* __restrict__ b_ih,   // [4H]
    const float* __restrict__ b_hh,   // [4H]
    float* __restrict__ out)          // [B, H]
{
    const int b    = blockIdx.x;
    const int l    = threadIdx.x;   // 0..63
    const int k    = l & 31;        // hidden unit index
    const int half = l >> 5;        // 0: rows (i_k, g_k); 1: rows (f_k, o_k)
    const int row0 = l;             // i_k (half0) or f_k (half1)
    const int row1 = l + 64;        // g_k (half0) or o_k (half1)

    __shared__ float x_lds[TSEQ + 4];

    // ---- one-time staging: x row into LDS (float4, coalesced) ----
    const float4* xrow4 = (const float4*)(x + (size_t)b * TSEQ);
    float4* xl4 = (float4*)x_lds;
    #pragma unroll
    for (int j = 0; j < (TSEQ / 4) / 64; ++j)   // 8 iters
        xl4[j * 64 + l] = xrow4[j * 64 + l];
    if (l == 0) x_lds[TSEQ] = 0.0f;

    // ---- one-time: W_hh rows, PRE-SCALED so sigmoid = rcp(1+exp2(d)) ----
    // dot0 (i/f): scale by -log2e.  dot1: g (half0) needs tanh = 2*sigm(2x)-1
    // -> scale by -2*log2e; o (half1) -> scale by -log2e.
    const float sc0 = NL2E;
    const float sc1 = half ? NL2E : 2.0f * NL2E;

    v2f wp0[HSZ/2], wp1[HSZ/2];
    #pragma unroll
    for (int j = 0; j < HSZ; j += 4) {
        float4 a  = *(const float4*)(W_hh + row0 * HSZ + j);
        float4 c4 = *(const float4*)(W_hh + row1 * HSZ + j);
        wp0[j/2]     = make2(a.x * sc0,  a.y * sc0);
        wp0[j/2 + 1] = make2(a.z * sc0,  a.w * sc0);
        wp1[j/2]     = make2(c4.x * sc1, c4.y * sc1);
        wp1[j/2 + 1] = make2(c4.z * sc1, c4.w * sc1);
    }
    const float wx0   = W_ih[row0] * sc0;
    const float wx1   = W_ih[row1] * sc1;
    const float bias0 = (b_ih[row0] + b_hh[row0]) * sc0;
    const float bias1 = (b_ih[row1] + b_hh[row1]) * sc1;

    const float s1mul = half ? 1.0f : 2.0f;
    const float s1add = half ? 0.0f : -1.0f;

    float c  = 0.0f;   // cell state
    float hk = 0.0f;   // h_k valid in lanes 32..63

    __syncthreads();
    float xt = x_lds[0];

    #pragma unroll 1
    for (int t = 0; t < TSEQ; ++t) {
        // ---- broadcast h (lanes 32..63) as consecutive pairs ----
        v2f hp[HSZ/2];
        #pragma unroll
        for (int m = 0; m < HSZ/2; ++m) {
            hp[m].x = readlane_f(hk, 32 + 2*m);
            hp[m].y = readlane_f(hk, 32 + 2*m + 1);
        }

        float xt_next = x_lds[t + 1];   // prefetch, latency hidden

        // ---- dot0 first (i/f), so its sigmoid hides under dot1's FMAs ----
        v2f q0 = make2(fmaf(wx0, xt, bias0), 0.f);
        v2f q1 = make2(0.f, 0.f), q2 = make2(0.f, 0.f), q3 = make2(0.f, 0.f);
        #pragma unroll
        for (int m = 0; m < HSZ/2; m += 4) {
            q0 = PKFMA(wp0[m],   hp[m],   q0);
            q1 = PKFMA(wp0[m+1], hp[m+1], q1);
            q2 = PKFMA(wp0[m+2], hp[m+2], q2);
            q3 = PKFMA(wp0[m+3], hp[m+3], q3);
        }
        v2f r0 = (q0 + q1) + (q2 + q3);
        float d0 = r0.x + r0.y;                   // pre-scaled
        float a0 = hw_rcp(1.0f + hw_exp2(d0));    // sigmoid(i/f)

        // ---- dot1 (g/o) ----
        v2f u0 = make2(fmaf(wx1, xt, bias1), 0.f);
        v2f u1 = make2(0.f, 0.f), u2 = make2(0.f, 0.f), u3 = make2(0.f, 0.f);
        #pragma unroll
        for (int m = 0; m < HSZ/2; m += 4) {
            u0 = PKFMA(wp1[m],   hp[m],   u0);
            u1 = PKFMA(wp1[m+1], hp[m+1], u1);
            u2 = PKFMA(wp1[m+2], hp[m+2], u2);
            u3 = PKFMA(wp1[m+3], hp[m+3], u3);
        }
        v2f r1 = (u0 + u1) + (u2 + u3);
        float d1 = r1.x + r1.y;
        float a1 = fmaf(s1mul, hw_rcp(1.0f + hw_exp2(d1)), s1add); // tanh(g)/sigm(o)

        // half0 contributes i*g, half1 contributes f*c; cross-half SUM = c_new
        float v  = a0 * (half ? c : a1);
        float cn = half_sum(v);
        c = cn;

        float th = fmaf(2.0f, hw_rcp(1.0f + hw_exp2(cn * (2.0f * NL2E))), -1.0f); // tanh(c)
        hk = a1 * th;   // valid (o*tanh(c)) in lanes 32..63

        xt = xt_next;
    }

    if (half) out[b * HSZ + k] = hk;
}

extern "C" void kernel_launch(void* const* d_in, const int* in_sizes, int n_in,
                              void* d_out, int out_size, void* d_ws, size_t ws_size,
                              hipStream_t stream) {
    const float* x    = (const float*)d_in[0];
    const float* W_ih = (const float*)d_in[1];
    const float* W_hh = (const float*)d_in[2];
    const float* b_ih = (const float*)d_in[3];
    const float* b_hh = (const float*)d_in[4];
    float* out = (float*)d_out;

    lstm_last_kernel<<<NBATCH, 64, 0, stream>>>(x, W_ih, W_hh, b_ih, b_hh, out);
}